// Round 11
// baseline (111.190 us; speedup 1.0000x reference)
//
#include <hip/hip_runtime.h>
#include <stdint.h>

#define KN 9
#define HH 64
#define WW 64
#define CC 128
#define FF 128
#define TM 64      // pixels per block (one full image row)
#define NT 512     // threads per block (8 waves)
#define LDK 128    // LDS K-stride (bf16). No pad; XOR swizzle kills conflicts.

typedef __bf16 bf16x8 __attribute__((ext_vector_type(8)));
typedef float f32x4 __attribute__((ext_vector_type(4)));
typedef unsigned short us8 __attribute__((ext_vector_type(8)));
typedef unsigned short us4 __attribute__((ext_vector_type(4)));

// Reference tap layout (verified R3): stack(meshgrid(ij)).reshape(-1,2) pairs
// the C-order flatten of (2,3,3) across the I/J boundary:
//   taps = (0,0)(0,1)(1,1)(2,2)(2,0)(1,2)(0,1)(2,0)(1,2)
__constant__ float c_init_i[KN] = {0.f,0.f,1.f,2.f,2.f,1.f,0.f,2.f,1.f};
__constant__ float c_init_j[KN] = {0.f,1.f,1.f,2.f,0.f,2.f,1.f,0.f,2.f};

static __device__ inline unsigned short f2bf(float f) {
    union { float f; unsigned u; } v; v.f = f;
    unsigned r = v.u + 0x7fffu + ((v.u >> 16) & 1u);  // RNE
    return (unsigned short)(r >> 16);
}
static __device__ inline float bf2f(unsigned short h) {
    union { unsigned u; float f; } v; v.u = ((unsigned)h) << 16;
    return v.f;
}

// Fused prep: blocks [0,144) transpose+quantize W (KN,C,F)->(KN,F,C) bf16;
// blocks [144, 144+4096) quantize x fp32->bf16 (4 elems/thread).
__global__ void prep_kernel(const float* __restrict__ Wk, const float* __restrict__ x,
                            unsigned short* __restrict__ Wt, unsigned short* __restrict__ xq) {
    if (blockIdx.x < KN * 16) {
        __shared__ unsigned short t[32][33];
        const int tid = threadIdx.x;
        const int n  = blockIdx.x >> 4;
        const int tf = blockIdx.x & 3;
        const int tc = (blockIdx.x >> 2) & 3;
        const int g  = tid >> 5;
        const int l  = tid & 31;
#pragma unroll
        for (int r = 0; r < 4; ++r) {
            int cl = g * 4 + r;
            t[cl][l] = f2bf(Wk[(n << 14) + ((tc * 32 + cl) << 7) + (tf * 32 + l)]);
        }
        __syncthreads();
#pragma unroll
        for (int r = 0; r < 4; ++r) {
            int fl = g * 4 + r;
            Wt[(n << 14) + ((tf * 32 + fl) << 7) + (tc * 32 + l)] = t[l][fl];
        }
    } else {
        int idx = (blockIdx.x - KN * 16) * 256 + threadIdx.x;
        const float4 v = ((const float4*)x)[idx];
        us4 o;
        o.x = f2bf(v.x); o.y = f2bf(v.y); o.z = f2bf(v.z); o.w = f2bf(v.w);
        ((us4*)xq)[idx] = o;
    }
}

__launch_bounds__(NT, 6)   // <=85 VGPR so 3 blocks/CU (LDS allows exactly 3)
__global__ void deform_kernel(const unsigned short* __restrict__ xq,
                              const float* __restrict__ off,
                              const unsigned short* __restrict__ Wt,
                              const float* __restrict__ bias,
                              float* __restrict__ out) {
    // XOR-swizzled layout: 16B group g of row r stored at group (g ^ (r&7)).
    // Row stride 256B (= 0 mod 32 banks) would be 16-way conflicted raw, but
    // the swizzle maps the MFMA read pattern (row=*+col, group=ks*4+quad) and
    // the staging write pattern to 2-way (free, m136).
    __shared__ unsigned short As[TM][LDK];   // deform tile, bf16, M x K
    __shared__ unsigned short Bt[FF][LDK];   // W tap, bf16, N x K (B^T layout)
    __shared__ float cY[TM][KN];
    __shared__ float cX[TM][KN];
    // 16384 + 32768 + 2304 + 2304 = 53760 B; x3 = 161280 <= 163840 -> 3 blocks/CU

    const int tid = threadIdx.x;
    // XCD swizzle (verified R5: FETCH 196->10.5 MB): image b -> XCD b.
    const int bb   = blockIdx.x & 7;
    const int hh   = blockIdx.x >> 3;
    const int pix0 = (bb << 12) + (hh << 6);

    for (int t = tid; t < TM * KN; t += NT) {
        int p = t & (TM - 1);
        int n = t >> 6;
        const float* op = off + (size_t)(pix0 + p) * (2 * KN) + 2 * n;
        float y = (float)(hh - 1) + c_init_i[n] + op[0];
        float x = (float)(p - 1) + c_init_j[n] + op[1];
        cY[p][n] = fminf(fmaxf(y, 0.f), 63.f);
        cX[p][n] = fminf(fmaxf(x, 0.f), 63.f);
    }
    __syncthreads();

    const int wave = tid >> 6;
    const int lane = tid & 63;
    const int quad = lane >> 4;
    const int col  = lane & 15;
    const int s7   = col & 7;            // row&7 for all rows this lane touches
    const int mtile = (wave & 1) * 32;   // 2 M-supertiles of 32 pixels
    const int ntile = (wave >> 1) * 32;  // 4 N-supertiles of 32 filters

    f32x4 acc[2][2];
#pragma unroll
    for (int a = 0; a < 2; ++a)
#pragma unroll
        for (int b = 0; b < 2; ++b) acc[a][b] = (f32x4){0.f, 0.f, 0.f, 0.f};

    const unsigned short* bbase = xq + ((size_t)bb << 19);  // b * 64*64*128

    // issue the 4 bf16 corner loads (us8 = 8 channels) for unit k of tap n
    auto issueA = [&](int n, int k, us8* pc) {
        int i  = tid + k * NT;       // 1024 units: 64 pixels x 16 ch-groups
        int p  = i >> 4;
        int cg = (i & 15) * 8;       // channel group in xq (unswizzled)
        float y = cY[p][n], x = cX[p][n];
        int y0 = (int)floorf(y), x0 = (int)floorf(x);
        int y1 = (int)ceilf(y),  x1 = (int)ceilf(x);
        pc[0] = *(const us8*)(bbase + ((((y0 << 6) + x0) << 7) + cg));  // lt
        pc[1] = *(const us8*)(bbase + ((((y1 << 6) + x0) << 7) + cg));  // rt
        pc[2] = *(const us8*)(bbase + ((((y0 << 6) + x1) << 7) + cg));  // lb
        pc[3] = *(const us8*)(bbase + ((((y1 << 6) + x1) << 7) + cg));  // rb
    };
    // interp 8 channels fp32, pack to As at the swizzled group
    auto consumeA = [&](int n, int k, const us8* pc) {
        int i  = tid + k * NT;
        int p  = i >> 4;
        int g  = i & 15;
        float y = cY[p][n], x = cX[p][n];
        float fy = y - floorf(y), fx = x - floorf(x);
        us8 pk;
#pragma unroll
        for (int c = 0; c < 8; ++c) {
            float vlt = bf2f(pc[0][c]), vrt = bf2f(pc[1][c]);
            float vlb = bf2f(pc[2][c]), vrb = bf2f(pc[3][c]);
            float vt = vlt + (vrt - vlt) * fy;
            float vb = vlb + (vrb - vlb) * fy;
            pk[c] = f2bf(vt + (vb - vt) * fx);
        }
        *(us8*)&As[p][(g ^ (p & 7)) * 8] = pk;
    };

    for (int n = 0; n < KN; ++n) {
        // ---- stage Bt: copy of Wt[n] (N x K, bf16), swizzled write ----
        const unsigned short* Wn = Wt + n * (CC * FF);
#pragma unroll
        for (int k = 0; k < 4; ++k) {
            int i2 = tid + k * NT;
            int f  = i2 >> 4;
            int g  = i2 & 15;
            *(us8*)&Bt[f][(g ^ (f & 7)) * 8] = *(const us8*)(Wn + f * CC + g * 8);
        }
        // ---- gather: 2 units/thread, both issued before first consume ----
        us8 u0[4], u1[4];
        issueA(n, 0, u0);
        issueA(n, 1, u1);
        consumeA(n, 0, u0);
        consumeA(n, 1, u1);
        __syncthreads();   // As/Bt ready

        // ---- MFMA: 32(M) x 32(N) wave tile, 4 K-steps of 32 ----
#pragma unroll
        for (int ks = 0; ks < 4; ++ks) {
            const int ga = ((ks * 4 + quad) ^ s7) * 8;   // swizzled group offset
            bf16x8 a0 = __builtin_bit_cast(bf16x8, *(const us8*)(&As[mtile + col][ga]));
            bf16x8 a1 = __builtin_bit_cast(bf16x8, *(const us8*)(&As[mtile + 16 + col][ga]));
            bf16x8 b0 = __builtin_bit_cast(bf16x8, *(const us8*)(&Bt[ntile + col][ga]));
            bf16x8 b1 = __builtin_bit_cast(bf16x8, *(const us8*)(&Bt[ntile + 16 + col][ga]));
            acc[0][0] = __builtin_amdgcn_mfma_f32_16x16x32_bf16(a0, b0, acc[0][0], 0, 0, 0);
            acc[0][1] = __builtin_amdgcn_mfma_f32_16x16x32_bf16(a0, b1, acc[0][1], 0, 0, 0);
            acc[1][0] = __builtin_amdgcn_mfma_f32_16x16x32_bf16(a1, b0, acc[1][0], 0, 0, 0);
            acc[1][1] = __builtin_amdgcn_mfma_f32_16x16x32_bf16(a1, b1, acc[1][1], 0, 0, 0);
        }
        __syncthreads();   // protect As/Bt overwrite next tap
    }

    // ---- epilogue: C/D layout col=lane&15, row=quad*4+reg (HW-verified) ----
#pragma unroll
    for (int b = 0; b < 2; ++b) {
        int f = ntile + b * 16 + col;
        float bv = bias[f];
#pragma unroll
        for (int a = 0; a < 2; ++a) {
#pragma unroll
            for (int r = 0; r < 4; ++r) {
                int pr = pix0 + mtile + a * 16 + quad * 4 + r;
                out[(size_t)pr * FF + f] = acc[a][b][r] + bv;
            }
        }
    }
}

extern "C" void kernel_launch(void* const* d_in, const int* in_sizes, int n_in,
                              void* d_out, int out_size, void* d_ws, size_t ws_size,
                              hipStream_t stream) {
    const float* x    = (const float*)d_in[0];
    const float* off  = (const float*)d_in[1];
    const float* Wk   = (const float*)d_in[2];
    const float* bias = (const float*)d_in[3];
    float* out = (float*)d_out;
    unsigned short* Wt = (unsigned short*)d_ws;                   // 294912 B
    unsigned short* xq = (unsigned short*)d_ws + (KN * CC * FF);  // 8.4 MB bf16 x

    prep_kernel<<<KN * 16 + (8 * HH * WW * CC) / 4 / 256, 256, 0, stream>>>(Wk, x, Wt, xq);
    deform_kernel<<<(8 * HH * WW) / TM, NT, 0, stream>>>(xq, off, Wt, bias, out);
}